// Round 1
// 212.006 us; speedup vs baseline: 1.0238x; 1.0238x over previous
//
#include <hip/hip_runtime.h>
#include <hip/hip_bf16.h>
#include <stdint.h>

#define NTOK 4096
#define DIM  256
#define NH   8
#define HD   32
#define MAXNNZ 512   // per-row neighbor list capacity (mean ~205)

typedef __attribute__((ext_vector_type(8))) short short8;
typedef __attribute__((ext_vector_type(4))) float float4v;
typedef unsigned short u16;
typedef unsigned int u32;

__device__ __forceinline__ float bf2f(u16 u) {
    union { u32 u; float f; } c; c.u = ((u32)u) << 16; return c.f;
}
__device__ __forceinline__ u16 f2bf(float f) {        // RNE
    union { float f; u32 u; } c; c.f = f;
    u32 u = c.u;
    u = u + 0x7FFFu + ((u >> 16) & 1u);
    return (u16)(u >> 16);
}
// unpack a packed bf16 pair (u32) to two f32 without shifts on the hi half
__device__ __forceinline__ float blo(u32 c) {
    union { u32 u; float f; } x; x.u = c << 16; return x.f;
}
__device__ __forceinline__ float bhi(u32 c) {
    union { u32 u; float f; } x; x.u = c & 0xFFFF0000u; return x.f;
}

// ---------------- kernel A: x (f32) -> bf16 ----------------
__global__ void x_to_bf16(const float* __restrict__ x, u16* __restrict__ xb) {
    int i = (blockIdx.x * blockDim.x + threadIdx.x) * 4;
    float4 v = *(const float4*)(x + i);
    ushort4 o;
    o.x = f2bf(v.x); o.y = f2bf(v.y); o.z = f2bf(v.z); o.w = f2bf(v.w);
    *(ushort4*)(xb + i) = o;
}

// ---------------- kernel 0: transpose weights (f32 256x256 -> bf16 WT) ----------------
__global__ void transpose_w(const float* __restrict__ Wq, const float* __restrict__ Wk,
                            const float* __restrict__ Wv, const float* __restrict__ Wo,
                            u16* __restrict__ WT) {
    const float* srcs[4] = {Wq, Wk, Wv, Wo};
    const float* W = srcs[blockIdx.y];
    int o = blockIdx.x, i = threadIdx.x;
    WT[blockIdx.y * 65536 + o * 256 + i] = f2bf(W[i * 256 + o]);
}

// ---------------- kernel 1: adj (f32) -> per-row neighbor lists ----------------
__global__ __launch_bounds__(256) void adj_to_list(const float* __restrict__ adj,
                                                   u16* __restrict__ NL,
                                                   u32* __restrict__ NC) {
    __shared__ u32 cnt;
    int row = blockIdx.x, t = threadIdx.x;
    if (t == 0) cnt = 0;
    __syncthreads();
    const float4* rp = (const float4*)(adj + (size_t)row * NTOK);
    u16* lbase = NL + (size_t)row * MAXNNZ;
#pragma unroll
    for (int i = 0; i < 4; ++i) {
        float4 v = rp[i * 256 + t];
        u32 m = 0;
        if (v.x != 0.f) m |= 1u;
        if (v.y != 0.f) m |= 2u;
        if (v.z != 0.f) m |= 4u;
        if (v.w != 0.f) m |= 8u;
        if (m) {
            int p = __popc(m);
            u32 base = atomicAdd(&cnt, (u32)p);
            int col0 = (i * 256 + t) * 4;
            while (m) {
                int j = __builtin_ctz(m);
                m &= m - 1;
                if (base < MAXNNZ) lbase[base] = (u16)(col0 + j);
                ++base;
            }
        }
    }
    __syncthreads();
    if (t == 0) NC[row] = (cnt < MAXNNZ) ? cnt : MAXNNZ;
}

// ---------------- kernel 2: QKV projection (bf16 inputs, row-major Q/K/V) ----------------
__global__ __launch_bounds__(64) void qkv_gemm(
    const u16* __restrict__ xb,
    const u16* __restrict__ WT,
    const float* __restrict__ bq, const float* __restrict__ bk, const float* __restrict__ bv,
    u16* __restrict__ Q, u16* __restrict__ K, u16* __restrict__ V) {
    int lane = threadIdx.x, quad = lane >> 4, l16 = lane & 15;
    int mtile = blockIdx.x, ntile = blockIdx.y, mat = blockIdx.z;
    const float* bias = (mat == 0) ? bq : (mat == 1) ? bk : bv;
    const u16* arow = xb + (size_t)(mtile * 16 + l16) * DIM + quad * 8;
    const u16* brow = WT + (size_t)mat * 65536 + (size_t)(ntile * 16 + l16) * DIM + quad * 8;
    float4v acc = {0.f, 0.f, 0.f, 0.f};
#pragma unroll
    for (int k0 = 0; k0 < DIM; k0 += 32) {
        short8 af = *(const short8*)(arow + k0);
        short8 bf = *(const short8*)(brow + k0);
        acc = __builtin_amdgcn_mfma_f32_16x16x32_bf16(af, bf, acc, 0, 0, 0);
    }
    int n = ntile * 16 + l16;
    float bb = bias[n];
    const float sc = (mat == 0) ? 0.25503635559913516f : 1.0f;  // 1/sqrt(32)*log2e
    u16* dst = (mat == 0) ? Q : (mat == 1) ? K : V;
#pragma unroll
    for (int r = 0; r < 4; ++r) {
        int m = mtile * 16 + quad * 4 + r;
        dst[(size_t)m * DIM + n] = f2bf((acc[r] + bb) * sc);
    }
}

// ---------------- kernel 3: SPARSE attention, lane-per-(head,neighbor) ----------------
// One wave per query row. Lane layout: head h = lane&7, neighbor-slot s = lane>>3.
// Each lane owns a complete (neighbor, head) pair: full 32-dim K/V head slice,
// dot product entirely in-lane (4 independent FMA chains), exp2, private O[32].
// NO cross-lane ops inside the loop (the old 3-shuffles-per-neighbor serial chain
// is gone); one 96-shfl butterfly per row at the end. Tail is branchless
// (index clamp + e=0 mask); next batch's index is prefetched.
#define UNPK8(C, B) do { \
    q[B+0]=blo(C.x); q[B+1]=bhi(C.x); q[B+2]=blo(C.y); q[B+3]=bhi(C.y); \
    q[B+4]=blo(C.z); q[B+5]=bhi(C.z); q[B+6]=blo(C.w); q[B+7]=bhi(C.w); } while(0)

#define DOT8(C, A, B) do { \
    A = fmaf(blo(C.x), q[B+0], A); A = fmaf(bhi(C.x), q[B+1], A); \
    A = fmaf(blo(C.y), q[B+2], A); A = fmaf(bhi(C.y), q[B+3], A); \
    A = fmaf(blo(C.z), q[B+4], A); A = fmaf(bhi(C.z), q[B+5], A); \
    A = fmaf(blo(C.w), q[B+6], A); A = fmaf(bhi(C.w), q[B+7], A); } while(0)

#define PV8(C, B) do { \
    O[B+0]=fmaf(e, blo(C.x), O[B+0]); O[B+1]=fmaf(e, bhi(C.x), O[B+1]); \
    O[B+2]=fmaf(e, blo(C.y), O[B+2]); O[B+3]=fmaf(e, bhi(C.y), O[B+3]); \
    O[B+4]=fmaf(e, blo(C.z), O[B+4]); O[B+5]=fmaf(e, bhi(C.z), O[B+5]); \
    O[B+6]=fmaf(e, blo(C.w), O[B+6]); O[B+7]=fmaf(e, bhi(C.w), O[B+7]); } while(0)

__global__ __launch_bounds__(256, 4) void sparse_attn(
    const u16* __restrict__ Q, const u16* __restrict__ K, const u16* __restrict__ V,
    const u16* __restrict__ NL, const u32* __restrict__ NC,
    u16* __restrict__ AO) {
    int row = blockIdx.x * 4 + (threadIdx.x >> 6);
    int lane = threadIdx.x & 63;
    int h = lane & 7;        // head: consecutive lanes share a gathered row -> coalesced
    int s = lane >> 3;       // neighbor slot 0..7

    // Q head-slice -> 32 f32 (Q was pre-scaled by 1/sqrt(HD)*log2e in qkv_gemm)
    const uint4* qp = (const uint4*)(Q + (size_t)row * DIM + h * HD);
    uint4 qq0 = qp[0], qq1 = qp[1], qq2 = qp[2], qq3 = qp[3];
    float q[32];
    UNPK8(qq0, 0); UNPK8(qq1, 8); UNPK8(qq2, 16); UNPK8(qq3, 24);

    float O[32];
#pragma unroll
    for (int i = 0; i < 32; ++i) O[i] = 0.f;
    float lsum = 0.f;

    int nnz = (int)NC[row];                 // >= 1 (self-loop)
    const u16* lst = NL + (size_t)row * MAXNNZ;
    const u16* Kh = K + h * HD;
    const u16* Vh = V + h * HD;

    int jj = (s < nnz) ? s : (nnz - 1);
    int idx = lst[jj];
    for (int j0 = 0; j0 < nnz; j0 += 8) {
        bool valid = (j0 + s) < nnz;
        const uint4* kp = (const uint4*)(Kh + (size_t)idx * DIM);
        const uint4* vp = (const uint4*)(Vh + (size_t)idx * DIM);
        uint4 k0 = kp[0], k1 = kp[1], k2 = kp[2], k3 = kp[3];
        uint4 v0 = vp[0], v1 = vp[1], v2 = vp[2], v3 = vp[3];
        int jn = j0 + 8 + s;
        jn = (jn < nnz) ? jn : (nnz - 1);
        idx = lst[jn];                      // prefetch next batch's index

        float a0 = 0.f, a1 = 0.f, a2 = 0.f, a3 = 0.f;   // 4 independent chains
        DOT8(k0, a0, 0); DOT8(k1, a1, 8); DOT8(k2, a2, 16); DOT8(k3, a3, 24);
        float sd = (a0 + a1) + (a2 + a3);
        float e = __builtin_amdgcn_exp2f(sd);
        e = valid ? e : 0.f;
        lsum += e;
        PV8(v0, 0); PV8(v1, 8); PV8(v2, 16); PV8(v3, 24);
    }

    // reduce over the 8 slots of each head (lanes differ in bits 3..5)
#pragma unroll
    for (int i = 0; i < 32; ++i) O[i] += __shfl_xor(O[i], 8, 64);
#pragma unroll
    for (int i = 0; i < 32; ++i) O[i] += __shfl_xor(O[i], 16, 64);
#pragma unroll
    for (int i = 0; i < 32; ++i) O[i] += __shfl_xor(O[i], 32, 64);
    lsum += __shfl_xor(lsum, 8, 64);
    lsum += __shfl_xor(lsum, 16, 64);
    lsum += __shfl_xor(lsum, 32, 64);

    if (s == 0) {                            // lanes 0..7 write the 512B row
        float inv = 1.0f / lsum;
        u32 w[16];
#pragma unroll
        for (int i = 0; i < 16; ++i) {
            u32 lo16 = (u32)f2bf(O[2 * i] * inv);
            u32 hi16 = (u32)f2bf(O[2 * i + 1] * inv);
            w[i] = lo16 | (hi16 << 16);
        }
        uint4* dst = (uint4*)(AO + (size_t)row * DIM + h * HD);
        dst[0] = make_uint4(w[0], w[1], w[2], w[3]);
        dst[1] = make_uint4(w[4], w[5], w[6], w[7]);
        dst[2] = make_uint4(w[8], w[9], w[10], w[11]);
        dst[3] = make_uint4(w[12], w[13], w[14], w[15]);
    }
}

// ---------------- kernel 4: output projection (f32 out) ----------------
__global__ __launch_bounds__(64) void out_gemm(
    const u16* __restrict__ AO, const u16* __restrict__ WTo, const float* __restrict__ bo,
    float* __restrict__ out) {
    int lane = threadIdx.x, quad = lane >> 4, l16 = lane & 15;
    int mtile = blockIdx.x, ntile = blockIdx.y;
    const u16* arow = AO + (size_t)(mtile * 16 + l16) * DIM + quad * 8;
    const u16* brow = WTo + (size_t)(ntile * 16 + l16) * DIM + quad * 8;
    float4v acc = {0.f, 0.f, 0.f, 0.f};
#pragma unroll
    for (int k0 = 0; k0 < DIM; k0 += 32) {
        short8 af = *(const short8*)(arow + k0);
        short8 bf = *(const short8*)(brow + k0);
        acc = __builtin_amdgcn_mfma_f32_16x16x32_bf16(af, bf, acc, 0, 0, 0);
    }
    int n = ntile * 16 + l16;
    float bb = bo[n];
#pragma unroll
    for (int r = 0; r < 4; ++r)
        out[(size_t)(mtile * 16 + quad * 4 + r) * DIM + n] = acc[r] + bb;
}

extern "C" void kernel_launch(void* const* d_in, const int* in_sizes, int n_in,
                              void* d_out, int out_size, void* d_ws, size_t ws_size,
                              hipStream_t stream) {
    const float* x   = (const float*)d_in[0];
    const float* adj = (const float*)d_in[1];
    const float* Wq  = (const float*)d_in[2];
    const float* bq  = (const float*)d_in[3];
    const float* Wk  = (const float*)d_in[4];
    const float* bk  = (const float*)d_in[5];
    const float* Wv  = (const float*)d_in[6];
    const float* bv  = (const float*)d_in[7];
    const float* Wo  = (const float*)d_in[8];
    const float* bo  = (const float*)d_in[9];

    char* ws = (char*)d_ws;
    const size_t MB = 1u << 20;
    u16* Q   = (u16*)(ws);                          // 2 MB
    u16* K   = (u16*)(ws + 2 * MB);                 // 2 MB
    u16* V   = (u16*)(ws + 4 * MB);                 // 2 MB
    u16* AO  = (u16*)(ws + 6 * MB);                 // 2 MB
    u16* WT  = (u16*)(ws + 8 * MB);                 // 512 KB
    u16* XB  = (u16*)(ws + 8 * MB + 512 * 1024);    // 2 MB
    u16* NL  = (u16*)(ws + 11 * MB);                // 4 MB neighbor lists
    u32* NC  = (u32*)(ws + 15 * MB);                // 16 KB counts

    x_to_bf16<<<dim3(1024), 256, 0, stream>>>(x, XB);
    transpose_w<<<dim3(256, 4), 256, 0, stream>>>(Wq, Wk, Wv, Wo, WT);
    adj_to_list<<<dim3(4096), 256, 0, stream>>>(adj, NL, NC);
    qkv_gemm<<<dim3(256, 16, 3), 64, 0, stream>>>(XB, WT, bq, bk, bv, Q, K, V);
    sparse_attn<<<dim3(1024), 256, 0, stream>>>(Q, K, V, NL, NC, AO);
    out_gemm<<<dim3(256, 16), 64, 0, stream>>>(AO, WT + 3 * 65536, bo, (float*)d_out);
}

// Round 2
// 199.874 us; speedup vs baseline: 1.0859x; 1.0607x over previous
//
#include <hip/hip_runtime.h>
#include <hip/hip_bf16.h>
#include <stdint.h>

#define NTOK 4096
#define DIM  256
#define NH   8
#define HD   32
#define MAXNNZ 512   // per-row neighbor list capacity (mean ~205)

typedef __attribute__((ext_vector_type(8))) short short8;
typedef __attribute__((ext_vector_type(4))) float float4v;
typedef unsigned short u16;
typedef unsigned int u32;

__device__ __forceinline__ float bf2f(u16 u) {
    union { u32 u; float f; } c; c.u = ((u32)u) << 16; return c.f;
}
__device__ __forceinline__ u16 f2bf(float f) {        // RNE
    union { float f; u32 u; } c; c.f = f;
    u32 u = c.u;
    u = u + 0x7FFFu + ((u >> 16) & 1u);
    return (u16)(u >> 16);
}
// unpack a packed bf16 pair (u32) to two f32 without shifts on the hi half
__device__ __forceinline__ float blo(u32 c) {
    union { u32 u; float f; } x; x.u = c << 16; return x.f;
}
__device__ __forceinline__ float bhi(u32 c) {
    union { u32 u; float f; } x; x.u = c & 0xFFFF0000u; return x.f;
}

// ---------------- kernel A: x (f32) -> bf16 ----------------
__global__ void x_to_bf16(const float* __restrict__ x, u16* __restrict__ xb) {
    int i = (blockIdx.x * blockDim.x + threadIdx.x) * 4;
    float4 v = *(const float4*)(x + i);
    ushort4 o;
    o.x = f2bf(v.x); o.y = f2bf(v.y); o.z = f2bf(v.z); o.w = f2bf(v.w);
    *(ushort4*)(xb + i) = o;
}

// ---------------- kernel 0: transpose weights (f32 256x256 -> bf16 WT) ----------------
__global__ void transpose_w(const float* __restrict__ Wq, const float* __restrict__ Wk,
                            const float* __restrict__ Wv, const float* __restrict__ Wo,
                            u16* __restrict__ WT) {
    const float* srcs[4] = {Wq, Wk, Wv, Wo};
    const float* W = srcs[blockIdx.y];
    int o = blockIdx.x, i = threadIdx.x;
    WT[blockIdx.y * 65536 + o * 256 + i] = f2bf(W[i * 256 + o]);
}

// ---------------- kernel 1: adj (f32) -> per-row neighbor lists ----------------
__global__ __launch_bounds__(256) void adj_to_list(const float* __restrict__ adj,
                                                   u16* __restrict__ NL,
                                                   u32* __restrict__ NC) {
    __shared__ u32 cnt;
    int row = blockIdx.x, t = threadIdx.x;
    if (t == 0) cnt = 0;
    __syncthreads();
    const float4* rp = (const float4*)(adj + (size_t)row * NTOK);
    u16* lbase = NL + (size_t)row * MAXNNZ;
#pragma unroll
    for (int i = 0; i < 4; ++i) {
        float4 v = rp[i * 256 + t];
        u32 m = 0;
        if (v.x != 0.f) m |= 1u;
        if (v.y != 0.f) m |= 2u;
        if (v.z != 0.f) m |= 4u;
        if (v.w != 0.f) m |= 8u;
        if (m) {
            int p = __popc(m);
            u32 base = atomicAdd(&cnt, (u32)p);
            int col0 = (i * 256 + t) * 4;
            while (m) {
                int j = __builtin_ctz(m);
                m &= m - 1;
                if (base < MAXNNZ) lbase[base] = (u16)(col0 + j);
                ++base;
            }
        }
    }
    __syncthreads();
    if (t == 0) NC[row] = (cnt < MAXNNZ) ? cnt : MAXNNZ;
}

// ---------------- kernel 2: QKV projection (bf16 inputs, row-major Q/K/V) ----------------
__global__ __launch_bounds__(64) void qkv_gemm(
    const u16* __restrict__ xb,
    const u16* __restrict__ WT,
    const float* __restrict__ bq, const float* __restrict__ bk, const float* __restrict__ bv,
    u16* __restrict__ Q, u16* __restrict__ K, u16* __restrict__ V) {
    int lane = threadIdx.x, quad = lane >> 4, l16 = lane & 15;
    int mtile = blockIdx.x, ntile = blockIdx.y, mat = blockIdx.z;
    const float* bias = (mat == 0) ? bq : (mat == 1) ? bk : bv;
    const u16* arow = xb + (size_t)(mtile * 16 + l16) * DIM + quad * 8;
    const u16* brow = WT + (size_t)mat * 65536 + (size_t)(ntile * 16 + l16) * DIM + quad * 8;
    float4v acc = {0.f, 0.f, 0.f, 0.f};
#pragma unroll
    for (int k0 = 0; k0 < DIM; k0 += 32) {
        short8 af = *(const short8*)(arow + k0);
        short8 bf = *(const short8*)(brow + k0);
        acc = __builtin_amdgcn_mfma_f32_16x16x32_bf16(af, bf, acc, 0, 0, 0);
    }
    int n = ntile * 16 + l16;
    float bb = bias[n];
    const float sc = (mat == 0) ? 0.25503635559913516f : 1.0f;  // 1/sqrt(32)*log2e
    u16* dst = (mat == 0) ? Q : (mat == 1) ? K : V;
#pragma unroll
    for (int r = 0; r < 4; ++r) {
        int m = mtile * 16 + quad * 4 + r;
        dst[(size_t)m * DIM + n] = f2bf((acc[r] + bb) * sc);
    }
}

// ---------------- kernel 3: SPARSE attention, coalesced row-pair gathers ----------------
// One wave per query row, neighbors processed 2 at a time (a "pair"), 2 pairs/iter.
// Lane layout: p = lane>>5 (which neighbor of the pair), t = lane&31 (16B chunk of
// the 512B K/V row; head h = t>>2, quarter = t&3).
// KEY: one global_load_dwordx4 now reads 2 FULL CONTIGUOUS rows (32 lanes x 16B each
// half-wave) -> 16 coalesced sector-requests/instr instead of 64 scattered ones
// (old layout put all 64 lanes in 64 distinct 64B sectors -> TCP request-bound:
// VALUBusy 33%, HBM 4%, dur flat). 8x fewer requests per neighbor.
// Per-head dot via 2-shfl butterfly over the 4-lane quarter group; O/lsum are
// per-parity partials, reduced across halves (shfl_xor 32) once at the end.
__global__ __launch_bounds__(256, 4) void sparse_attn(
    const u16* __restrict__ Q, const u16* __restrict__ K, const u16* __restrict__ V,
    const u16* __restrict__ NL, const u32* __restrict__ NC,
    u16* __restrict__ AO) {
    int row = blockIdx.x * 4 + (threadIdx.x >> 6);
    int lane = threadIdx.x & 63;
    int p = lane >> 5;       // neighbor parity within a pair
    int t = lane & 31;       // 16B chunk index within the 512B row

    // Q slice: 8 contiguous dims at t*8 (head t>>2, quarter t&3).
    // Q was pre-scaled by 1/sqrt(HD)*log2e in qkv_gemm.
    uint4 qq = *(const uint4*)(Q + (size_t)row * DIM + t * 8);
    float q0 = blo(qq.x), q1 = bhi(qq.x), q2 = blo(qq.y), q3 = bhi(qq.y);
    float q4 = blo(qq.z), q5 = bhi(qq.z), q6 = blo(qq.w), q7 = bhi(qq.w);

    float O[8];
#pragma unroll
    for (int i = 0; i < 8; ++i) O[i] = 0.f;
    float lsum = 0.f;

    int nnz = (int)NC[row];                 // >= 1 (self-loop)
    const u16* lst = NL + (size_t)row * MAXNNZ;
    const u16* Kt = K + t * 8;              // lane's chunk offset folded in
    const u16* Vt = V + t * 8;

#define PAIR_BODY(kk, vv, e_valid)                                               \
    {                                                                            \
        float a = 0.f, b = 0.f;                                                  \
        a = fmaf(blo(kk.x), q0, a); b = fmaf(bhi(kk.x), q1, b);                  \
        a = fmaf(blo(kk.y), q2, a); b = fmaf(bhi(kk.y), q3, b);                  \
        a = fmaf(blo(kk.z), q4, a); b = fmaf(bhi(kk.z), q5, b);                  \
        a = fmaf(blo(kk.w), q6, a); b = fmaf(bhi(kk.w), q7, b);                  \
        float s = a + b;                                                         \
        s += __shfl_xor(s, 1, 64);                                               \
        s += __shfl_xor(s, 2, 64);      /* full 32-dim head dot in all 4 lanes */\
        float e = __builtin_amdgcn_exp2f(s);                                     \
        e = (e_valid) ? e : 0.f;                                                 \
        lsum += e;                                                               \
        O[0] = fmaf(e, blo(vv.x), O[0]); O[1] = fmaf(e, bhi(vv.x), O[1]);        \
        O[2] = fmaf(e, blo(vv.y), O[2]); O[3] = fmaf(e, bhi(vv.y), O[3]);        \
        O[4] = fmaf(e, blo(vv.z), O[4]); O[5] = fmaf(e, bhi(vv.z), O[5]);        \
        O[6] = fmaf(e, blo(vv.w), O[6]); O[7] = fmaf(e, bhi(vv.w), O[7]);        \
    }

    // indices for pair A (nbrs i2+0,i2+1) and pair B (nbrs i2+2,i2+3),
    // prefetched one iteration ahead to hide idx->gather dependency.
    u32 wA = *(const u32*)(lst);                               // i2 always even
    u32 wB = (nnz > 2) ? *(const u32*)(lst + 2) : wA;
    for (int i2 = 0; i2 < nnz; i2 += 4) {
        bool vA = (i2 + p) < nnz;
        bool vB = (i2 + 2 + p) < nnz;
        int lo = (int)(wA & 0xFFFFu);                          // always a valid nbr
        int iA = p ? (int)(wA >> 16) : lo;
        int iB = p ? (int)(wB >> 16) : (int)(wB & 0xFFFFu);
        if (!vA) iA = lo;
        if (!vB) iB = lo;

        // prefetch next iteration's index words (clamped pointers; values
        // only consumed when in range)
        int in0 = i2 + 4, in2 = i2 + 6;
        u32 wAn = *(const u32*)(lst + ((in0 < nnz) ? in0 : 0));
        u32 wBn = *(const u32*)(lst + ((in2 < nnz) ? in2 : 0));

        // 4 coalesced row-gathers, all issued before compute
        uint4 kA = *(const uint4*)(Kt + (size_t)iA * DIM);
        uint4 vAv = *(const uint4*)(Vt + (size_t)iA * DIM);
        uint4 kB = *(const uint4*)(Kt + (size_t)iB * DIM);
        uint4 vBv = *(const uint4*)(Vt + (size_t)iB * DIM);

        PAIR_BODY(kA, vAv, vA)
        PAIR_BODY(kB, vBv, vB)

        wA = wAn; wB = wBn;
    }
#undef PAIR_BODY

    // combine the two parity halves (lanes differ in bit 5)
#pragma unroll
    for (int i = 0; i < 8; ++i) O[i] += __shfl_xor(O[i], 32, 64);
    lsum += __shfl_xor(lsum, 32, 64);

    if (p == 0) {                            // 32 lanes write the full 512B row
        float inv = 1.0f / lsum;
        u32 w0 = (u32)f2bf(O[0] * inv) | ((u32)f2bf(O[1] * inv) << 16);
        u32 w1 = (u32)f2bf(O[2] * inv) | ((u32)f2bf(O[3] * inv) << 16);
        u32 w2 = (u32)f2bf(O[4] * inv) | ((u32)f2bf(O[5] * inv) << 16);
        u32 w3 = (u32)f2bf(O[6] * inv) | ((u32)f2bf(O[7] * inv) << 16);
        *(uint4*)(AO + (size_t)row * DIM + t * 8) = make_uint4(w0, w1, w2, w3);
    }
}

// ---------------- kernel 4: output projection (f32 out) ----------------
__global__ __launch_bounds__(64) void out_gemm(
    const u16* __restrict__ AO, const u16* __restrict__ WTo, const float* __restrict__ bo,
    float* __restrict__ out) {
    int lane = threadIdx.x, quad = lane >> 4, l16 = lane & 15;
    int mtile = blockIdx.x, ntile = blockIdx.y;
    const u16* arow = AO + (size_t)(mtile * 16 + l16) * DIM + quad * 8;
    const u16* brow = WTo + (size_t)(ntile * 16 + l16) * DIM + quad * 8;
    float4v acc = {0.f, 0.f, 0.f, 0.f};
#pragma unroll
    for (int k0 = 0; k0 < DIM; k0 += 32) {
        short8 af = *(const short8*)(arow + k0);
        short8 bf = *(const short8*)(brow + k0);
        acc = __builtin_amdgcn_mfma_f32_16x16x32_bf16(af, bf, acc, 0, 0, 0);
    }
    int n = ntile * 16 + l16;
    float bb = bo[n];
#pragma unroll
    for (int r = 0; r < 4; ++r)
        out[(size_t)(mtile * 16 + quad * 4 + r) * DIM + n] = acc[r] + bb;
}

extern "C" void kernel_launch(void* const* d_in, const int* in_sizes, int n_in,
                              void* d_out, int out_size, void* d_ws, size_t ws_size,
                              hipStream_t stream) {
    const float* x   = (const float*)d_in[0];
    const float* adj = (const float*)d_in[1];
    const float* Wq  = (const float*)d_in[2];
    const float* bq  = (const float*)d_in[3];
    const float* Wk  = (const float*)d_in[4];
    const float* bk  = (const float*)d_in[5];
    const float* Wv  = (const float*)d_in[6];
    const float* bv  = (const float*)d_in[7];
    const float* Wo  = (const float*)d_in[8];
    const float* bo  = (const float*)d_in[9];

    char* ws = (char*)d_ws;
    const size_t MB = 1u << 20;
    u16* Q   = (u16*)(ws);                          // 2 MB
    u16* K   = (u16*)(ws + 2 * MB);                 // 2 MB
    u16* V   = (u16*)(ws + 4 * MB);                 // 2 MB
    u16* AO  = (u16*)(ws + 6 * MB);                 // 2 MB
    u16* WT  = (u16*)(ws + 8 * MB);                 // 512 KB
    u16* XB  = (u16*)(ws + 8 * MB + 512 * 1024);    // 2 MB
    u16* NL  = (u16*)(ws + 11 * MB);                // 4 MB neighbor lists
    u32* NC  = (u32*)(ws + 15 * MB);                // 16 KB counts

    x_to_bf16<<<dim3(1024), 256, 0, stream>>>(x, XB);
    transpose_w<<<dim3(256, 4), 256, 0, stream>>>(Wq, Wk, Wv, Wo, WT);
    adj_to_list<<<dim3(4096), 256, 0, stream>>>(adj, NL, NC);
    qkv_gemm<<<dim3(256, 16, 3), 64, 0, stream>>>(XB, WT, bq, bk, bv, Q, K, V);
    sparse_attn<<<dim3(1024), 256, 0, stream>>>(Q, K, V, NL, NC, AO);
    out_gemm<<<dim3(256, 16), 64, 0, stream>>>(AO, WT + 3 * 65536, bo, (float*)d_out);
}

// Round 3
// 196.957 us; speedup vs baseline: 1.1020x; 1.0148x over previous
//
#include <hip/hip_runtime.h>
#include <hip/hip_bf16.h>
#include <stdint.h>

#define NTOK 4096
#define DIM  256
#define NH   8
#define HD   32
#define MAXNNZ 512   // per-row neighbor list capacity (mean ~205)

typedef __attribute__((ext_vector_type(8))) short short8;
typedef __attribute__((ext_vector_type(4))) float float4v;
typedef unsigned short u16;
typedef unsigned int u32;

__device__ __forceinline__ float bf2f(u16 u) {
    union { u32 u; float f; } c; c.u = ((u32)u) << 16; return c.f;
}
__device__ __forceinline__ u16 f2bf(float f) {        // RNE
    union { float f; u32 u; } c; c.f = f;
    u32 u = c.u;
    u = u + 0x7FFFu + ((u >> 16) & 1u);
    return (u16)(u >> 16);
}
// unpack a packed bf16 pair (u32) to two f32 without shifts on the hi half
__device__ __forceinline__ float blo(u32 c) {
    union { u32 u; float f; } x; x.u = c << 16; return x.f;
}
__device__ __forceinline__ float bhi(u32 c) {
    union { u32 u; float f; } x; x.u = c & 0xFFFF0000u; return x.f;
}

// ---------------- kernel A: x (f32) -> bf16 ----------------
__global__ void x_to_bf16(const float* __restrict__ x, u16* __restrict__ xb) {
    int i = (blockIdx.x * blockDim.x + threadIdx.x) * 4;
    float4 v = *(const float4*)(x + i);
    ushort4 o;
    o.x = f2bf(v.x); o.y = f2bf(v.y); o.z = f2bf(v.z); o.w = f2bf(v.w);
    *(ushort4*)(xb + i) = o;
}

// ---------------- kernel 0: transpose weights (f32 256x256 -> bf16 WT) ----------------
__global__ void transpose_w(const float* __restrict__ Wq, const float* __restrict__ Wk,
                            const float* __restrict__ Wv, const float* __restrict__ Wo,
                            u16* __restrict__ WT) {
    const float* srcs[4] = {Wq, Wk, Wv, Wo};
    const float* W = srcs[blockIdx.y];
    int o = blockIdx.x, i = threadIdx.x;
    WT[blockIdx.y * 65536 + o * 256 + i] = f2bf(W[i * 256 + o]);
}

// ---------------- kernel 1: adj (f32) -> per-row neighbor lists ----------------
__global__ __launch_bounds__(256) void adj_to_list(const float* __restrict__ adj,
                                                   u16* __restrict__ NL,
                                                   u32* __restrict__ NC) {
    __shared__ u32 cnt;
    int row = blockIdx.x, t = threadIdx.x;
    if (t == 0) cnt = 0;
    __syncthreads();
    const float4* rp = (const float4*)(adj + (size_t)row * NTOK);
    u16* lbase = NL + (size_t)row * MAXNNZ;
#pragma unroll
    for (int i = 0; i < 4; ++i) {
        float4 v = rp[i * 256 + t];
        u32 m = 0;
        if (v.x != 0.f) m |= 1u;
        if (v.y != 0.f) m |= 2u;
        if (v.z != 0.f) m |= 4u;
        if (v.w != 0.f) m |= 8u;
        if (m) {
            int p = __popc(m);
            u32 base = atomicAdd(&cnt, (u32)p);
            int col0 = (i * 256 + t) * 4;
            while (m) {
                int j = __builtin_ctz(m);
                m &= m - 1;
                if (base < MAXNNZ) lbase[base] = (u16)(col0 + j);
                ++base;
            }
        }
    }
    __syncthreads();
    if (t == 0) NC[row] = (cnt < MAXNNZ) ? cnt : MAXNNZ;
}

// ---------------- kernel 2: QKV projection (bf16 inputs, row-major Q/K/V) ----------------
__global__ __launch_bounds__(64) void qkv_gemm(
    const u16* __restrict__ xb,
    const u16* __restrict__ WT,
    const float* __restrict__ bq, const float* __restrict__ bk, const float* __restrict__ bv,
    u16* __restrict__ Q, u16* __restrict__ K, u16* __restrict__ V) {
    int lane = threadIdx.x, quad = lane >> 4, l16 = lane & 15;
    int mtile = blockIdx.x, ntile = blockIdx.y, mat = blockIdx.z;
    const float* bias = (mat == 0) ? bq : (mat == 1) ? bk : bv;
    const u16* arow = xb + (size_t)(mtile * 16 + l16) * DIM + quad * 8;
    const u16* brow = WT + (size_t)mat * 65536 + (size_t)(ntile * 16 + l16) * DIM + quad * 8;
    float4v acc = {0.f, 0.f, 0.f, 0.f};
#pragma unroll
    for (int k0 = 0; k0 < DIM; k0 += 32) {
        short8 af = *(const short8*)(arow + k0);
        short8 bf = *(const short8*)(brow + k0);
        acc = __builtin_amdgcn_mfma_f32_16x16x32_bf16(af, bf, acc, 0, 0, 0);
    }
    int n = ntile * 16 + l16;
    float bb = bias[n];
    const float sc = (mat == 0) ? 0.25503635559913516f : 1.0f;  // 1/sqrt(32)*log2e
    u16* dst = (mat == 0) ? Q : (mat == 1) ? K : V;
#pragma unroll
    for (int r = 0; r < 4; ++r) {
        int m = mtile * 16 + quad * 4 + r;
        dst[(size_t)m * DIM + n] = f2bf((acc[r] + bb) * sc);
    }
}

// ---------------- kernel 3: SPARSE attention, 2 waves per row (split list) ----------------
// Round-2 analysis: VALUBusy 59%, HBM 5%, VGPR 28, 4 waves/SIMD -> latency-bound
// with idle register file. This round: each row's neighbor list is split across
// TWO waves (contiguous halves, split point multiple of 4); grid 2048 blocks x 256
// threads = 32 waves/CU = 8/SIMD (full occupancy). Partials (O[8], lsum per
// 32-lane chunk) combine through 2.3 KB LDS (stride-9 floats -> conflict-free).
// Inner loop identical to round 2: coalesced row-pair gathers, 2-shfl head dot.
__global__ __launch_bounds__(256, 8) void sparse_attn(
    const u16* __restrict__ Q, const u16* __restrict__ K, const u16* __restrict__ V,
    const u16* __restrict__ NL, const u32* __restrict__ NC,
    u16* __restrict__ AO) {
    __shared__ float part[2][32][9];     // [row_in_block][t][O0..7, lsum] from wave half=1
    int tid  = threadIdx.x;
    int rb   = tid >> 7;                 // row within block (0/1)
    int half = (tid >> 6) & 1;           // which half of the neighbor list
    int lane = tid & 63;
    int p = lane >> 5;                   // neighbor parity within a pair
    int t = lane & 31;                   // 16B chunk index within the 512B row
    int row = blockIdx.x * 2 + rb;

    // Q slice: 8 contiguous dims at t*8 (pre-scaled by 1/sqrt(HD)*log2e in qkv_gemm)
    uint4 qq = *(const uint4*)(Q + (size_t)row * DIM + t * 8);
    float q0 = blo(qq.x), q1 = bhi(qq.x), q2 = blo(qq.y), q3 = bhi(qq.y);
    float q4 = blo(qq.z), q5 = bhi(qq.z), q6 = blo(qq.w), q7 = bhi(qq.w);

    float O[8];
#pragma unroll
    for (int i = 0; i < 8; ++i) O[i] = 0.f;
    float lsum = 0.f;

    int nnz = (int)NC[row];              // >= 1 (self-loop)
    const u16* lst = NL + (size_t)row * MAXNNZ;
    int nh    = ((nnz + 4) >> 3) << 2;   // split point, multiple of 4, ~nnz/2
    int begin = half ? nh : 0;
    int end   = half ? nnz : nh;
    const u16* Kt = K + t * 8;           // lane's chunk offset folded in
    const u16* Vt = V + t * 8;

#define PAIR_BODY(kk, vv, e_valid)                                               \
    {                                                                            \
        float a = 0.f, b = 0.f;                                                  \
        a = fmaf(blo(kk.x), q0, a); b = fmaf(bhi(kk.x), q1, b);                  \
        a = fmaf(blo(kk.y), q2, a); b = fmaf(bhi(kk.y), q3, b);                  \
        a = fmaf(blo(kk.z), q4, a); b = fmaf(bhi(kk.z), q5, b);                  \
        a = fmaf(blo(kk.w), q6, a); b = fmaf(bhi(kk.w), q7, b);                  \
        float s = a + b;                                                         \
        s += __shfl_xor(s, 1, 64);                                               \
        s += __shfl_xor(s, 2, 64);      /* full 32-dim head dot in all 4 lanes */\
        float e = __builtin_amdgcn_exp2f(s);                                     \
        e = (e_valid) ? e : 0.f;                                                 \
        lsum += e;                                                               \
        O[0] = fmaf(e, blo(vv.x), O[0]); O[1] = fmaf(e, bhi(vv.x), O[1]);        \
        O[2] = fmaf(e, blo(vv.y), O[2]); O[3] = fmaf(e, bhi(vv.y), O[3]);        \
        O[4] = fmaf(e, blo(vv.z), O[4]); O[5] = fmaf(e, bhi(vv.z), O[5]);        \
        O[6] = fmaf(e, blo(vv.w), O[6]); O[7] = fmaf(e, bhi(vv.w), O[7]);        \
    }

    if (begin < end) {
        // index words for pair A (begin+0,1) / pair B (begin+2,3), prefetched
        // one iteration ahead to hide the idx -> gather dependency.
        u32 wA = *(const u32*)(lst + begin);
        u32 wB = (begin + 2 < end) ? *(const u32*)(lst + begin + 2) : wA;
        for (int i2 = begin; i2 < end; i2 += 4) {
            bool vA = (i2 + p) < end;
            bool vB = (i2 + 2 + p) < end;
            int lo = (int)(wA & 0xFFFFu);                    // always a valid nbr
            int iA = p ? (int)(wA >> 16) : lo;
            int iB = p ? (int)(wB >> 16) : (int)(wB & 0xFFFFu);
            if (!vA) iA = lo;
            if (!vB) iB = lo;

            int in0 = i2 + 4, in2 = i2 + 6;
            u32 wAn = *(const u32*)(lst + ((in0 < end) ? in0 : begin));
            u32 wBn = *(const u32*)(lst + ((in2 < end) ? in2 : begin));

            // 4 coalesced row-pair gathers, issued before compute
            uint4 kA  = *(const uint4*)(Kt + (size_t)iA * DIM);
            uint4 vAv = *(const uint4*)(Vt + (size_t)iA * DIM);
            uint4 kB  = *(const uint4*)(Kt + (size_t)iB * DIM);
            uint4 vBv = *(const uint4*)(Vt + (size_t)iB * DIM);

            PAIR_BODY(kA, vAv, vA)
            PAIR_BODY(kB, vBv, vB)

            wA = wAn; wB = wBn;
        }
    }
#undef PAIR_BODY

    // combine the two parity halves (lanes differ in bit 5)
#pragma unroll
    for (int i = 0; i < 8; ++i) O[i] += __shfl_xor(O[i], 32, 64);
    lsum += __shfl_xor(lsum, 32, 64);

    // cross-wave combine through LDS (stride 9 floats: 9 coprime 32 -> no conflicts)
    if (half == 1 && p == 0) {
#pragma unroll
        for (int i = 0; i < 8; ++i) part[rb][t][i] = O[i];
        part[rb][t][8] = lsum;
    }
    __syncthreads();
    if (half == 0 && p == 0) {
#pragma unroll
        for (int i = 0; i < 8; ++i) O[i] += part[rb][t][i];
        lsum += part[rb][t][8];
        float inv = 1.0f / lsum;
        u32 w0 = (u32)f2bf(O[0] * inv) | ((u32)f2bf(O[1] * inv) << 16);
        u32 w1 = (u32)f2bf(O[2] * inv) | ((u32)f2bf(O[3] * inv) << 16);
        u32 w2 = (u32)f2bf(O[4] * inv) | ((u32)f2bf(O[5] * inv) << 16);
        u32 w3 = (u32)f2bf(O[6] * inv) | ((u32)f2bf(O[7] * inv) << 16);
        *(uint4*)(AO + (size_t)row * DIM + t * 8) = make_uint4(w0, w1, w2, w3);
    }
}

// ---------------- kernel 4: output projection (f32 out) ----------------
__global__ __launch_bounds__(64) void out_gemm(
    const u16* __restrict__ AO, const u16* __restrict__ WTo, const float* __restrict__ bo,
    float* __restrict__ out) {
    int lane = threadIdx.x, quad = lane >> 4, l16 = lane & 15;
    int mtile = blockIdx.x, ntile = blockIdx.y;
    const u16* arow = AO + (size_t)(mtile * 16 + l16) * DIM + quad * 8;
    const u16* brow = WTo + (size_t)(ntile * 16 + l16) * DIM + quad * 8;
    float4v acc = {0.f, 0.f, 0.f, 0.f};
#pragma unroll
    for (int k0 = 0; k0 < DIM; k0 += 32) {
        short8 af = *(const short8*)(arow + k0);
        short8 bf = *(const short8*)(brow + k0);
        acc = __builtin_amdgcn_mfma_f32_16x16x32_bf16(af, bf, acc, 0, 0, 0);
    }
    int n = ntile * 16 + l16;
    float bb = bo[n];
#pragma unroll
    for (int r = 0; r < 4; ++r)
        out[(size_t)(mtile * 16 + quad * 4 + r) * DIM + n] = acc[r] + bb;
}

extern "C" void kernel_launch(void* const* d_in, const int* in_sizes, int n_in,
                              void* d_out, int out_size, void* d_ws, size_t ws_size,
                              hipStream_t stream) {
    const float* x   = (const float*)d_in[0];
    const float* adj = (const float*)d_in[1];
    const float* Wq  = (const float*)d_in[2];
    const float* bq  = (const float*)d_in[3];
    const float* Wk  = (const float*)d_in[4];
    const float* bk  = (const float*)d_in[5];
    const float* Wv  = (const float*)d_in[6];
    const float* bv  = (const float*)d_in[7];
    const float* Wo  = (const float*)d_in[8];
    const float* bo  = (const float*)d_in[9];

    char* ws = (char*)d_ws;
    const size_t MB = 1u << 20;
    u16* Q   = (u16*)(ws);                          // 2 MB
    u16* K   = (u16*)(ws + 2 * MB);                 // 2 MB
    u16* V   = (u16*)(ws + 4 * MB);                 // 2 MB
    u16* AO  = (u16*)(ws + 6 * MB);                 // 2 MB
    u16* WT  = (u16*)(ws + 8 * MB);                 // 512 KB
    u16* XB  = (u16*)(ws + 8 * MB + 512 * 1024);    // 2 MB
    u16* NL  = (u16*)(ws + 11 * MB);                // 4 MB neighbor lists
    u32* NC  = (u32*)(ws + 15 * MB);                // 16 KB counts

    x_to_bf16<<<dim3(1024), 256, 0, stream>>>(x, XB);
    transpose_w<<<dim3(256, 4), 256, 0, stream>>>(Wq, Wk, Wv, Wo, WT);
    adj_to_list<<<dim3(4096), 256, 0, stream>>>(adj, NL, NC);
    qkv_gemm<<<dim3(256, 16, 3), 64, 0, stream>>>(XB, WT, bq, bk, bv, Q, K, V);
    sparse_attn<<<dim3(2048), 256, 0, stream>>>(Q, K, V, NL, NC, AO);
    out_gemm<<<dim3(256, 16), 64, 0, stream>>>(AO, WT + 3 * 65536, bo, (float*)d_out);
}

// Round 4
// 190.455 us; speedup vs baseline: 1.1396x; 1.0341x over previous
//
#include <hip/hip_runtime.h>
#include <hip/hip_bf16.h>
#include <stdint.h>

#define NTOK 4096
#define DIM  256
#define NH   8
#define HD   32
#define MAXNNZ 512   // per-row neighbor list capacity (mean ~205)

typedef __attribute__((ext_vector_type(8))) short short8;
typedef __attribute__((ext_vector_type(4))) float float4v;
typedef __attribute__((ext_vector_type(2))) float f32x2;
typedef __attribute__((ext_vector_type(2))) _Float16 h2;
typedef unsigned short u16;
typedef unsigned int u32;

__device__ __forceinline__ float bf2f(u16 u) {
    union { u32 u; float f; } c; c.u = ((u32)u) << 16; return c.f;
}
__device__ __forceinline__ u16 f2bf(float f) {        // RNE
    union { float f; u32 u; } c; c.f = f;
    u32 u = c.u;
    u = u + 0x7FFFu + ((u >> 16) & 1u);
    return (u16)(u >> 16);
}
__device__ __forceinline__ u16 f2h(float f) {         // f32 -> f16 bits
    union { _Float16 h; u16 u; } c; c.h = (_Float16)f; return c.u;
}
__device__ __forceinline__ h2 bch2(u32 v) {           // u32 -> half2
    union { u32 u; h2 h; } c; c.u = v; return c.h;
}
// unpack a packed bf16 pair (u32) to two f32 without shifts on the hi half
__device__ __forceinline__ float blo(u32 c) {
    union { u32 u; float f; } x; x.u = c << 16; return x.f;
}
__device__ __forceinline__ float bhi(u32 c) {
    union { u32 u; float f; } x; x.u = c & 0xFFFF0000u; return x.f;
}

// ---------------- kernel A: x (f32) -> bf16 ----------------
__global__ void x_to_bf16(const float* __restrict__ x, u16* __restrict__ xb) {
    int i = (blockIdx.x * blockDim.x + threadIdx.x) * 4;
    float4 v = *(const float4*)(x + i);
    ushort4 o;
    o.x = f2bf(v.x); o.y = f2bf(v.y); o.z = f2bf(v.z); o.w = f2bf(v.w);
    *(ushort4*)(xb + i) = o;
}

// ---------------- kernel 0: transpose weights (f32 256x256 -> bf16 WT) ----------------
__global__ void transpose_w(const float* __restrict__ Wq, const float* __restrict__ Wk,
                            const float* __restrict__ Wv, const float* __restrict__ Wo,
                            u16* __restrict__ WT) {
    const float* srcs[4] = {Wq, Wk, Wv, Wo};
    const float* W = srcs[blockIdx.y];
    int o = blockIdx.x, i = threadIdx.x;
    WT[blockIdx.y * 65536 + o * 256 + i] = f2bf(W[i * 256 + o]);
}

// ---------------- kernel 1: adj (f32) -> per-row neighbor lists ----------------
__global__ __launch_bounds__(256) void adj_to_list(const float* __restrict__ adj,
                                                   u16* __restrict__ NL,
                                                   u32* __restrict__ NC) {
    __shared__ u32 cnt;
    int row = blockIdx.x, t = threadIdx.x;
    if (t == 0) cnt = 0;
    __syncthreads();
    const float4* rp = (const float4*)(adj + (size_t)row * NTOK);
    u16* lbase = NL + (size_t)row * MAXNNZ;
#pragma unroll
    for (int i = 0; i < 4; ++i) {
        float4 v = rp[i * 256 + t];
        u32 m = 0;
        if (v.x != 0.f) m |= 1u;
        if (v.y != 0.f) m |= 2u;
        if (v.z != 0.f) m |= 4u;
        if (v.w != 0.f) m |= 8u;
        if (m) {
            int p = __popc(m);
            u32 base = atomicAdd(&cnt, (u32)p);
            int col0 = (i * 256 + t) * 4;
            while (m) {
                int j = __builtin_ctz(m);
                m &= m - 1;
                if (base < MAXNNZ) lbase[base] = (u16)(col0 + j);
                ++base;
            }
        }
    }
    __syncthreads();
    if (t == 0) NC[row] = (cnt < MAXNNZ) ? cnt : MAXNNZ;
}

// ---------------- kernel 2: QKV projection -----------------------------------
// Q, K written as f16 (feeds v_dot2_f32_f16 in sparse_attn; f16 has MORE
// mantissa than bf16 and values are O(1) -> strictly better precision).
// V stays bf16 (PV path unpacks via bit-ops).
__global__ __launch_bounds__(64) void qkv_gemm(
    const u16* __restrict__ xb,
    const u16* __restrict__ WT,
    const float* __restrict__ bq, const float* __restrict__ bk, const float* __restrict__ bv,
    u16* __restrict__ Q, u16* __restrict__ K, u16* __restrict__ V) {
    int lane = threadIdx.x, quad = lane >> 4, l16 = lane & 15;
    int mtile = blockIdx.x, ntile = blockIdx.y, mat = blockIdx.z;
    const float* bias = (mat == 0) ? bq : (mat == 1) ? bk : bv;
    const u16* arow = xb + (size_t)(mtile * 16 + l16) * DIM + quad * 8;
    const u16* brow = WT + (size_t)mat * 65536 + (size_t)(ntile * 16 + l16) * DIM + quad * 8;
    float4v acc = {0.f, 0.f, 0.f, 0.f};
#pragma unroll
    for (int k0 = 0; k0 < DIM; k0 += 32) {
        short8 af = *(const short8*)(arow + k0);
        short8 bf = *(const short8*)(brow + k0);
        acc = __builtin_amdgcn_mfma_f32_16x16x32_bf16(af, bf, acc, 0, 0, 0);
    }
    int n = ntile * 16 + l16;
    float bb = bias[n];
    const float sc = (mat == 0) ? 0.25503635559913516f : 1.0f;  // 1/sqrt(32)*log2e
    u16* dst = (mat == 0) ? Q : (mat == 1) ? K : V;
#pragma unroll
    for (int r = 0; r < 4; ++r) {
        int m = mtile * 16 + quad * 4 + r;
        float y = (acc[r] + bb) * sc;
        dst[(size_t)m * DIM + n] = (mat == 2) ? f2bf(y) : f2h(y);
    }
}

// ---------------- kernel 3: SPARSE attention, VALU-thinned ----------------
// Memory layout unchanged from round 3 (coalesced row-pair gathers, 2 waves/row,
// 8 waves/SIMD). Round-3 analysis: full occupancy, VALUBusy 66% -> ~32us of the
// 49us is pure VALU issue. This round thins the stream:
//   * QK dot via v_dot2_f32_f16 (Q,K stored f16): 17 -> 4 inst
//   * PV via float2 + elementwise_fma -> v_pk_fma_f32: 16 -> 12 inst
//   * main loop has NO validity selects (masked tail split off)
//   * readfirstlane(row/half) -> nnz/lst/begin/end wave-uniform -> index-word
//     prefetches become s_load (off the vector path)
//   * 32-bit element offsets, SGPR-base global loads
__global__ __launch_bounds__(256, 8) void sparse_attn(
    const u16* __restrict__ Q, const u16* __restrict__ K, const u16* __restrict__ V,
    const u16* __restrict__ NL, const u32* __restrict__ NC,
    u16* __restrict__ AO) {
    __shared__ float part[2][32][9];     // [row_in_block][t][O0..7, lsum] from wave half=1
    int tid  = threadIdx.x;
    int rb   = __builtin_amdgcn_readfirstlane(tid >> 7);         // row within block
    int half = __builtin_amdgcn_readfirstlane((tid >> 6) & 1);   // list half
    int lane = tid & 63;
    int p = lane >> 5;                   // neighbor parity within a pair
    int t = lane & 31;                   // 16B chunk index within the 512B row
    int row = __builtin_amdgcn_readfirstlane((int)blockIdx.x * 2 + rb);
    int pshift = p << 4;
    u32 tOff = (u32)(t * 8);             // element offset of this lane's chunk

    // Q slice (f16): 8 contiguous dims at t*8 (pre-scaled by 1/sqrt(HD)*log2e)
    uint4 qq = *(const uint4*)(Q + (size_t)row * DIM + t * 8);
    h2 qh0 = bch2(qq.x), qh1 = bch2(qq.y), qh2 = bch2(qq.z), qh3 = bch2(qq.w);

    f32x2 O0 = {0.f, 0.f}, O1 = {0.f, 0.f}, O2 = {0.f, 0.f}, O3 = {0.f, 0.f};
    float lsum = 0.f;

    int nnz = __builtin_amdgcn_readfirstlane((int)NC[row]);   // >= 1 (self-loop)
    const u16* lst = NL + (size_t)row * MAXNNZ;
    int nh    = ((nnz + 4) >> 3) << 2;   // split point, multiple of 4, ~nnz/2
    int begin = half ? nh : 0;
    int end   = half ? nnz : nh;

#define BODY(kk, vv, EVALID)                                                     \
    {                                                                            \
        float a = __builtin_amdgcn_fdot2(bch2(kk.x), qh0, 0.f, false);           \
        float b = __builtin_amdgcn_fdot2(bch2(kk.y), qh1, 0.f, false);           \
        a = __builtin_amdgcn_fdot2(bch2(kk.z), qh2, a, false);                   \
        b = __builtin_amdgcn_fdot2(bch2(kk.w), qh3, b, false);                   \
        float s = a + b;                                                         \
        s += __shfl_xor(s, 1, 64);                                               \
        s += __shfl_xor(s, 2, 64);      /* full 32-dim head dot in all 4 lanes */\
        float e = __builtin_amdgcn_exp2f(s);                                     \
        if (!(EVALID)) e = 0.f;          /* folds away in the main loop */       \
        lsum += e;                                                               \
        f32x2 ev = {e, e};                                                       \
        O0 = __builtin_elementwise_fma(ev, (f32x2){blo(vv.x), bhi(vv.x)}, O0);   \
        O1 = __builtin_elementwise_fma(ev, (f32x2){blo(vv.y), bhi(vv.y)}, O1);   \
        O2 = __builtin_elementwise_fma(ev, (f32x2){blo(vv.z), bhi(vv.z)}, O2);   \
        O3 = __builtin_elementwise_fma(ev, (f32x2){blo(vv.w), bhi(vv.w)}, O3);   \
    }

    if (begin < end) {
        // index words for pair A (i2,i2+1) / pair B (i2+2,i2+3); wave-uniform
        // addresses -> s_load; prefetched one iteration ahead.
        u32 wA = *(const u32*)(lst + begin);
        u32 wB = *(const u32*)(lst + begin + 2);
        int i2 = begin;
        for (; i2 + 4 <= end; i2 += 4) {
            u32 offA = (((wA >> pshift) & 0xFFFFu) << 8) + tOff;
            u32 offB = (((wB >> pshift) & 0xFFFFu) << 8) + tOff;
            u32 wAn = *(const u32*)(lst + i2 + 4);     // in-bounds of NL region
            u32 wBn = *(const u32*)(lst + i2 + 6);
            uint4 kA  = *(const uint4*)(K + offA);     // 2 full contiguous rows
            uint4 vAv = *(const uint4*)(V + offA);     // per wave -> coalesced
            uint4 kB  = *(const uint4*)(K + offB);
            uint4 vBv = *(const uint4*)(V + offB);
            BODY(kA, vAv, true)
            BODY(kB, vBv, true)
            wA = wAn; wB = wBn;
        }
        if (i2 < end) {                  // ragged tail, 1..3 neighbors, masked
            u32 lo = wA & 0xFFFFu;       // always a valid neighbor
            bool mA = (i2 + p) < end;
            bool mB = (i2 + 2 + p) < end;
            u32 idxA = mA ? ((wA >> pshift) & 0xFFFFu) : lo;
            u32 idxB = mB ? ((wB >> pshift) & 0xFFFFu) : lo;
            u32 offA = (idxA << 8) + tOff;
            u32 offB = (idxB << 8) + tOff;
            uint4 kA  = *(const uint4*)(K + offA);
            uint4 vAv = *(const uint4*)(V + offA);
            uint4 kB  = *(const uint4*)(K + offB);
            uint4 vBv = *(const uint4*)(V + offB);
            BODY(kA, vAv, mA)
            BODY(kB, vBv, mB)
        }
    }
#undef BODY

    float Of[8] = {O0.x, O0.y, O1.x, O1.y, O2.x, O2.y, O3.x, O3.y};
    // combine the two parity halves (lanes differ in bit 5)
#pragma unroll
    for (int i = 0; i < 8; ++i) Of[i] += __shfl_xor(Of[i], 32, 64);
    lsum += __shfl_xor(lsum, 32, 64);

    // cross-wave combine through LDS (stride 9 floats: 9 coprime 32 -> no conflicts)
    if (half == 1 && p == 0) {
#pragma unroll
        for (int i = 0; i < 8; ++i) part[rb][t][i] = Of[i];
        part[rb][t][8] = lsum;
    }
    __syncthreads();
    if (half == 0 && p == 0) {
#pragma unroll
        for (int i = 0; i < 8; ++i) Of[i] += part[rb][t][i];
        lsum += part[rb][t][8];
        float inv = 1.0f / lsum;
        u32 w0 = (u32)f2bf(Of[0] * inv) | ((u32)f2bf(Of[1] * inv) << 16);
        u32 w1 = (u32)f2bf(Of[2] * inv) | ((u32)f2bf(Of[3] * inv) << 16);
        u32 w2 = (u32)f2bf(Of[4] * inv) | ((u32)f2bf(Of[5] * inv) << 16);
        u32 w3 = (u32)f2bf(Of[6] * inv) | ((u32)f2bf(Of[7] * inv) << 16);
        *(uint4*)(AO + (size_t)row * DIM + t * 8) = make_uint4(w0, w1, w2, w3);
    }
}

// ---------------- kernel 4: output projection (f32 out) ----------------
__global__ __launch_bounds__(64) void out_gemm(
    const u16* __restrict__ AO, const u16* __restrict__ WTo, const float* __restrict__ bo,
    float* __restrict__ out) {
    int lane = threadIdx.x, quad = lane >> 4, l16 = lane & 15;
    int mtile = blockIdx.x, ntile = blockIdx.y;
    const u16* arow = AO + (size_t)(mtile * 16 + l16) * DIM + quad * 8;
    const u16* brow = WTo + (size_t)(ntile * 16 + l16) * DIM + quad * 8;
    float4v acc = {0.f, 0.f, 0.f, 0.f};
#pragma unroll
    for (int k0 = 0; k0 < DIM; k0 += 32) {
        short8 af = *(const short8*)(arow + k0);
        short8 bf = *(const short8*)(brow + k0);
        acc = __builtin_amdgcn_mfma_f32_16x16x32_bf16(af, bf, acc, 0, 0, 0);
    }
    int n = ntile * 16 + l16;
    float bb = bo[n];
#pragma unroll
    for (int r = 0; r < 4; ++r)
        out[(size_t)(mtile * 16 + quad * 4 + r) * DIM + n] = acc[r] + bb;
}

extern "C" void kernel_launch(void* const* d_in, const int* in_sizes, int n_in,
                              void* d_out, int out_size, void* d_ws, size_t ws_size,
                              hipStream_t stream) {
    const float* x   = (const float*)d_in[0];
    const float* adj = (const float*)d_in[1];
    const float* Wq  = (const float*)d_in[2];
    const float* bq  = (const float*)d_in[3];
    const float* Wk  = (const float*)d_in[4];
    const float* bk  = (const float*)d_in[5];
    const float* Wv  = (const float*)d_in[6];
    const float* bv  = (const float*)d_in[7];
    const float* Wo  = (const float*)d_in[8];
    const float* bo  = (const float*)d_in[9];

    char* ws = (char*)d_ws;
    const size_t MB = 1u << 20;
    u16* Q   = (u16*)(ws);                          // 2 MB
    u16* K   = (u16*)(ws + 2 * MB);                 // 2 MB
    u16* V   = (u16*)(ws + 4 * MB);                 // 2 MB
    u16* AO  = (u16*)(ws + 6 * MB);                 // 2 MB
    u16* WT  = (u16*)(ws + 8 * MB);                 // 512 KB
    u16* XB  = (u16*)(ws + 8 * MB + 512 * 1024);    // 2 MB
    u16* NL  = (u16*)(ws + 11 * MB);                // 4 MB neighbor lists
    u32* NC  = (u32*)(ws + 15 * MB);                // 16 KB counts

    x_to_bf16<<<dim3(1024), 256, 0, stream>>>(x, XB);
    transpose_w<<<dim3(256, 4), 256, 0, stream>>>(Wq, Wk, Wv, Wo, WT);
    adj_to_list<<<dim3(4096), 256, 0, stream>>>(adj, NL, NC);
    qkv_gemm<<<dim3(256, 16, 3), 64, 0, stream>>>(XB, WT, bq, bk, bv, Q, K, V);
    sparse_attn<<<dim3(2048), 256, 0, stream>>>(Q, K, V, NL, NC, AO);
    out_gemm<<<dim3(256, 16), 64, 0, stream>>>(AO, WT + 3 * 65536, bo, (float*)d_out);
}